// Round 5
// baseline (400.361 us; speedup 1.0000x reference)
//
#include <hip/hip_runtime.h>
#include <hip/hip_fp16.h>

typedef _Float16 half8 __attribute__((ext_vector_type(8)));
typedef float floatx4 __attribute__((ext_vector_type(4)));
typedef unsigned int uintx4 __attribute__((ext_vector_type(4)));

// ---------------------------------------------------------------------------
// GCN 2-layer, pull-style. R5: nontemporal streaming loads (protect L2 for the
// scatter segment), dinv folded into GEMM epilogue (agg needs no dinv gather).
//   H1' = dinv .* (x@W1)  [fp16]
//   x2  = relu( dn*(sum H1'[s] + H1'[n]) + b1 )  [fp16]
//   H2' = dinv .* (x2@W2) [fp16] ; out = dn*(sum H2'[s] + H2'[n]) + b2 [fp32]
// ---------------------------------------------------------------------------

__device__ inline int ntload_i(const int* p) { return __builtin_nontemporal_load(p); }

// ---- CSR build, destination-range partitioned: XCD (blockIdx&7) owns a
// ---- contiguous node range; streams read nt so scatter lines stay in L2.
__global__ __launch_bounds__(256) void count2_kernel(const int* __restrict__ col,
                                                     int* __restrict__ cnt,
                                                     int E, int N, int NS, int CHUNKS) {
    const int xcd = blockIdx.x & 7;
    const int lo = xcd * NS;
    const int hi = min(lo + NS, N);
    const int stride = CHUNKS * 256;
    for (int e = (blockIdx.x >> 3) * 256 + threadIdx.x; e < E; e += stride) {
        int c = ntload_i(col + e);
        if (c >= lo && c < hi) atomicAdd(&cnt[c], 1);
    }
}

__global__ __launch_bounds__(256) void fill2_kernel(const int* __restrict__ row,
                                                    const int* __restrict__ col,
                                                    int* __restrict__ cursor,
                                                    int* __restrict__ srcSorted,
                                                    int E, int N, int NS, int CHUNKS) {
    const int xcd = blockIdx.x & 7;
    const int lo = xcd * NS;
    const int hi = min(lo + NS, N);
    const int stride = CHUNKS * 256;
    for (int e = (blockIdx.x >> 3) * 256 + threadIdx.x; e < E; e += stride) {
        int c = ntload_i(col + e);
        if (c >= lo && c < hi) {
            int idx = atomicAdd(&cursor[c], 1);
            srcSorted[idx] = ntload_i(row + e);
        }
    }
}

__global__ __launch_bounds__(256) void dinv_kernel(const int* __restrict__ cnt,
                                                   float* __restrict__ dinv, int N) {
    int i = blockIdx.x * 256 + threadIdx.x;
    if (i < N) dinv[i] = rsqrtf((float)cnt[i] + 1.0f);   // +1 self-loop
}

__global__ __launch_bounds__(256) void scan_block_kernel(const int* __restrict__ cnt,
                                                         int* __restrict__ base,
                                                         int* __restrict__ sums, int N) {
    __shared__ int s[256];
    int tid = threadIdx.x;
    int i = blockIdx.x * 256 + tid;
    int v = (i < N) ? cnt[i] : 0;
    s[tid] = v;
    __syncthreads();
#pragma unroll
    for (int d = 1; d < 256; d <<= 1) {
        int t = (tid >= d) ? s[tid - d] : 0;
        __syncthreads();
        s[tid] += t;
        __syncthreads();
    }
    if (i < N) base[i] = s[tid] - v;
    if (tid == 255) sums[blockIdx.x] = s[255];
}

__global__ __launch_bounds__(512) void scan_sums_kernel(int* __restrict__ sums, int nb) {
    __shared__ int s[512];
    int tid = threadIdx.x;
    int v = (tid < nb) ? sums[tid] : 0;
    s[tid] = v;
    __syncthreads();
#pragma unroll
    for (int d = 1; d < 512; d <<= 1) {
        int t = (tid >= d) ? s[tid - d] : 0;
        __syncthreads();
        s[tid] += t;
        __syncthreads();
    }
    if (tid < nb) sums[tid] = s[tid] - v;
}

__global__ __launch_bounds__(256) void add_offsets_kernel(int* __restrict__ base,
                                                          const int* __restrict__ sums,
                                                          const int* __restrict__ cnt, int N) {
    int i = blockIdx.x * 256 + threadIdx.x;
    if (i < N) {
        int v = base[i] + sums[i >> 8];
        base[i] = v;
        if (i == N - 1) base[N] = v + cnt[i]; // = E
    }
}

// ---- W [128 x C] fp32 row-major -> WT [C x 128] fp16, k-index XOR-swizzled
__global__ __launch_bounds__(256) void wtrans_kernel(const float* __restrict__ W,
                                                     __half* __restrict__ WT, int C) {
    int idx = blockIdx.x * 256 + threadIdx.x;
    if (idx >= 128 * C) return;
    int k = idx / C, c = idx % C;
    float v = W[idx];
    WT[c * 128 + (k ^ ((c & 7) << 3))] = __float2half_rn(v);
}

// ---- fp16 MFMA GEMM + dinv-scaled epilogue:
// H[r][:] = half( dinv[r] * (X[r][:] @ W) ),  fp32 accum.
template <int COLS, typename XT>
__global__ __launch_bounds__(256) void mfma_gemm(const XT* __restrict__ X,
                                                 const __half* __restrict__ WT,
                                                 const float* __restrict__ dinv,
                                                 __half* __restrict__ H, int N) {
    __shared__ _Float16 sX[64 * 128];
    __shared__ _Float16 sW[COLS * 128];
    const int tid = threadIdx.x;
    const int row0 = blockIdx.x * 64;

    {
        const uintx4* src = (const uintx4*)WT;
        uintx4* dst = (uintx4*)sW;
        for (int i = tid; i < COLS * 16; i += 256) dst[i] = src[i];
    }
    for (int cidx = tid; cidx < 1024; cidx += 256) {
        int r = cidx >> 4, k8 = cidx & 15;
        int gr = row0 + r;
        half8 h;
#pragma unroll
        for (int q = 0; q < 8; ++q) h[q] = (_Float16)0.f;
        if (gr < N) {
            if constexpr (sizeof(XT) == 4) {
                const floatx4* p = (const floatx4*)((const float*)X + (size_t)gr * 128 + k8 * 8);
                floatx4 f0 = __builtin_nontemporal_load(p);
                floatx4 f1 = __builtin_nontemporal_load(p + 1);
#pragma unroll
                for (int q = 0; q < 4; ++q) {
                    h[q] = (_Float16)f0[q];
                    h[4 + q] = (_Float16)f1[q];
                }
            } else {
                const half8* p = (const half8*)((const _Float16*)X + (size_t)gr * 128 + k8 * 8);
                h = __builtin_nontemporal_load(p);
            }
        }
        *(half8*)(sX + r * 128 + ((k8 * 8) ^ ((r & 7) << 3))) = h;
    }
    __syncthreads();

    const int w = tid >> 6;
    const int lane = tid & 63;
    const int l15 = lane & 15, l4 = lane >> 4;
    constexpr int WCOLS = COLS / 2;
    constexpr int NCB = WCOLS / 16;
    const int wr = (w >> 1) * 32;
    const int wc = (w & 1) * WCOLS;

    half8 a[2][4];
#pragma unroll
    for (int rb = 0; rb < 2; ++rb) {
        int r = wr + rb * 16 + l15;
#pragma unroll
        for (int kb = 0; kb < 4; ++kb)
            a[rb][kb] = *(const half8*)(sX + r * 128 + ((kb * 32 + l4 * 8) ^ ((r & 7) << 3)));
    }

    floatx4 acc[2][NCB];
#pragma unroll
    for (int rb = 0; rb < 2; ++rb)
#pragma unroll
        for (int cb = 0; cb < NCB; ++cb) acc[rb][cb] = (floatx4)(0.f);

#pragma unroll
    for (int cb = 0; cb < NCB; ++cb) {
        int c = wc + cb * 16 + l15;
#pragma unroll
        for (int kb = 0; kb < 4; ++kb) {
            half8 b = *(const half8*)(sW + c * 128 + ((kb * 32 + l4 * 8) ^ ((c & 7) << 3)));
#pragma unroll
            for (int rb = 0; rb < 2; ++rb)
                acc[rb][cb] = __builtin_amdgcn_mfma_f32_16x16x32_f16(a[rb][kb], b, acc[rb][cb], 0, 0, 0);
        }
    }

#pragma unroll
    for (int rb = 0; rb < 2; ++rb) {
        float dv[4];
#pragma unroll
        for (int r = 0; r < 4; ++r) {
            int gr = row0 + wr + rb * 16 + l4 * 4 + r;
            dv[r] = (gr < N) ? dinv[gr] : 0.f;
        }
#pragma unroll
        for (int cb = 0; cb < NCB; ++cb)
#pragma unroll
            for (int r = 0; r < 4; ++r) {
                int gr = row0 + wr + rb * 16 + l4 * 4 + r;
                if (gr < N) {
                    int gc = wc + cb * 16 + l15;
                    H[(size_t)gr * COLS + gc] = __float2half_rn(acc[rb][cb][r] * dv[r]);
                }
            }
    }
}

__device__ inline void add8(float (&a)[8], uintx4 v) {
    union { uintx4 u; __half2 h[4]; } cv;
    cv.u = v;
#pragma unroll
    for (int q = 0; q < 4; ++q) {
        a[2 * q]     += __low2float(cv.h[q]);
        a[2 * q + 1] += __high2float(cv.h[q]);
    }
}

// ---- Pull aggregation over pre-scaled H': out[n] = dn*(sum H'[s] + H'[n]) + b
template <int C, bool RELU, typename OT>
__global__ __launch_bounds__(256) void agg_kernel(const __half* __restrict__ H16,
                                                  const int* __restrict__ srcSorted,
                                                  const int* __restrict__ base,
                                                  const float* __restrict__ dinv,
                                                  const float* __restrict__ b,
                                                  OT* __restrict__ out, int N) {
    constexpr int G = C / 8;
    constexpr int NPB = 256 / G;
    const int lane = threadIdx.x % G;
    const int sub = threadIdx.x / G;
    const int n = blockIdx.x * NPB + sub;
    if (n >= N) return;

    const uintx4* H4 = (const uintx4*)H16;
    const int s = base[n];
    const int e = base[n + 1];

    float acc[8];
#pragma unroll
    for (int q = 0; q < 8; ++q) acc[q] = 0.f;

    int i = s;
    for (; i + 3 < e; i += 4) {
        int s0 = ntload_i(srcSorted + i);
        int s1 = ntload_i(srcSorted + i + 1);
        int s2 = ntload_i(srcSorted + i + 2);
        int s3 = ntload_i(srcSorted + i + 3);
        uintx4 v0 = H4[(size_t)s0 * G + lane];
        uintx4 v1 = H4[(size_t)s1 * G + lane];
        uintx4 v2 = H4[(size_t)s2 * G + lane];
        uintx4 v3 = H4[(size_t)s3 * G + lane];
        add8(acc, v0);
        add8(acc, v1);
        add8(acc, v2);
        add8(acc, v3);
    }
    for (; i < e; ++i) {
        int s0 = ntload_i(srcSorted + i);
        add8(acc, H4[(size_t)s0 * G + lane]);
    }

    const float dn = dinv[n];
    uintx4 hv = H4[(size_t)n * G + lane];
    union { uintx4 u; __half2 h[4]; } cv;
    cv.u = hv;
    float o[8];
#pragma unroll
    for (int q = 0; q < 4; ++q) {
        o[2 * q]     = dn * (acc[2 * q]     + __low2float(cv.h[q]));
        o[2 * q + 1] = dn * (acc[2 * q + 1] + __high2float(cv.h[q]));
    }
    const float4 bb0 = ((const float4*)b)[lane * 2];
    const float4 bb1 = ((const float4*)b)[lane * 2 + 1];
    o[0] += bb0.x; o[1] += bb0.y; o[2] += bb0.z; o[3] += bb0.w;
    o[4] += bb1.x; o[5] += bb1.y; o[6] += bb1.z; o[7] += bb1.w;
    if (RELU) {
#pragma unroll
        for (int q = 0; q < 8; ++q) o[q] = fmaxf(o[q], 0.f);
    }
    if constexpr (sizeof(OT) == 2) {
        half8 st;
#pragma unroll
        for (int q = 0; q < 8; ++q) st[q] = (_Float16)o[q];
        *(half8*)((_Float16*)out + (size_t)n * C + lane * 8) = st;
    } else {
        float4* op = (float4*)((float*)out + (size_t)n * C + lane * 8);
        op[0] = make_float4(o[0], o[1], o[2], o[3]);
        op[1] = make_float4(o[4], o[5], o[6], o[7]);
    }
}

static inline int cdiv(long long a, long long b) { return (int)((a + b - 1) / b); }

extern "C" void kernel_launch(void* const* d_in, const int* in_sizes, int n_in,
                              void* d_out, int out_size, void* d_ws, size_t ws_size,
                              hipStream_t stream) {
    const float* x  = (const float*)d_in[0];
    const float* W1 = (const float*)d_in[1];
    const float* b1 = (const float*)d_in[2];
    const float* W2 = (const float*)d_in[3];
    const float* b2 = (const float*)d_in[4];
    const int*   ei = (const int*)d_in[5];

    const int N = in_sizes[0] / 128;   // 100000
    const int E = in_sizes[5] / 2;     // 1600000
    const int* rows = ei;              // edge_index[0] = source
    const int* cols = ei + E;          // edge_index[1] = target

    const int nbN = cdiv(N, 256);      // 391
    const int NS = cdiv(N, 8);         // 12500 nodes per XCD range
    const int CHUNKS = 128;            // blocks per range-pass

    char* ws = (char*)d_ws;
    size_t off = 0;
    auto alloc = [&](size_t bytes) {
        size_t p = off;
        off = (off + bytes + 255) & ~(size_t)255;
        return p;
    };
    int*      cnt    = (int*)(ws + alloc((size_t)N * 4));
    int*      cursor = (int*)(ws + alloc((size_t)(N + 1) * 4));
    int*      base   = (int*)(ws + alloc((size_t)(N + 1) * 4));
    int*      sums   = (int*)(ws + alloc((size_t)512 * 4));
    float*    dinv   = (float*)(ws + alloc((size_t)N * 4));
    int*      srcS   = (int*)(ws + alloc((size_t)E * 4));
    __half*   WT1    = (__half*)(ws + alloc((size_t)128 * 128 * 2));
    __half*   WT2    = (__half*)(ws + alloc((size_t)128 * 64 * 2));
    __half*   H16    = (__half*)(ws + alloc((size_t)N * 128 * 2));  // h1', then h2'
    __half*   X2h    = (__half*)(ws + alloc((size_t)N * 128 * 2));  // relu'd layer-1
    (void)ws_size;

    float* OUT = (float*)d_out;

    // --- CSR by destination + dinv (shared by both layers) ---
    hipMemsetAsync(cnt, 0, (size_t)N * 4, stream);
    count2_kernel<<<8 * CHUNKS, 256, 0, stream>>>(cols, cnt, E, N, NS, CHUNKS);
    dinv_kernel<<<nbN, 256, 0, stream>>>(cnt, dinv, N);
    scan_block_kernel<<<nbN, 256, 0, stream>>>(cnt, base, sums, N);
    scan_sums_kernel<<<1, 512, 0, stream>>>(sums, nbN);
    add_offsets_kernel<<<nbN, 256, 0, stream>>>(base, sums, cnt, N);
    hipMemcpyAsync(cursor, base, (size_t)N * 4, hipMemcpyDeviceToDevice, stream);
    fill2_kernel<<<8 * CHUNKS, 256, 0, stream>>>(rows, cols, cursor, srcS, E, N, NS, CHUNKS);

    // --- weight prep (fp16, transposed, swizzled) ---
    wtrans_kernel<<<cdiv(128 * 128, 256), 256, 0, stream>>>(W1, WT1, 128);
    wtrans_kernel<<<cdiv(128 * 64, 256), 256, 0, stream>>>(W2, WT2, 64);

    // --- layer 1 ---
    mfma_gemm<128, float><<<cdiv(N, 64), 256, 0, stream>>>(x, WT1, dinv, H16, N);
    agg_kernel<128, true, __half><<<cdiv(N, 16), 256, 0, stream>>>(H16, srcS, base, dinv, b1, X2h, N);

    // --- layer 2 ---
    mfma_gemm<64, _Float16><<<cdiv(N, 64), 256, 0, stream>>>((const _Float16*)X2h, WT2, dinv, H16, N);
    agg_kernel<64, false, float><<<cdiv(N, 32), 256, 0, stream>>>(H16, srcS, base, dinv, b2, OUT, N);
}

// Round 6
// 391.255 us; speedup vs baseline: 1.0233x; 1.0233x over previous
//
#include <hip/hip_runtime.h>
#include <hip/hip_fp16.h>

typedef _Float16 half8 __attribute__((ext_vector_type(8)));
typedef float floatx4 __attribute__((ext_vector_type(4)));
typedef unsigned int uintx4 __attribute__((ext_vector_type(4)));

// ---------------------------------------------------------------------------
// GCN 2-layer, pull-style. R6: two-phase bucketed CSR build (one streaming
// pass + XCD-local count/fill), dinv folded into GEMM epilogue, no nt hints.
//   H1' = dinv .* (x@W1)  [fp16]
//   x2  = relu( dn*(sum H1'[s] + H1'[n]) + b1 )  [fp16]
//   H2' = dinv .* (x2@W2) [fp16] ; out = dn*(sum H2'[s] + H2'[n]) + b2 [fp32]
// ---------------------------------------------------------------------------

#define NBUK 8

// ---- Phase A: one pass over the edge list; partition edges into 8
// ---- destination ranges (packed (row,col)); per-block LDS histogram +
// ---- global cursor reservation -> chunk-contiguous full-line writes.
__global__ __launch_bounds__(256) void bucket_kernel(const int* __restrict__ rows,
                                                     const int* __restrict__ cols,
                                                     int E, int NS, int CAP,
                                                     int* __restrict__ bcur,
                                                     uint2* __restrict__ bdata) {
    __shared__ int hcnt[NBUK];
    __shared__ int hbase[NBUK];
    const int tid = threadIdx.x;
    const int chunk0 = blockIdx.x * 2048;
    if (tid < NBUK) hcnt[tid] = 0;
    __syncthreads();
    int myr[8], myc[8], myb[8];
#pragma unroll
    for (int q = 0; q < 8; ++q) {
        int e = chunk0 + q * 256 + tid;
        myb[q] = -1;
        if (e < E) {
            myr[q] = rows[e];
            myc[q] = cols[e];
            int b = (int)((unsigned)myc[q] / (unsigned)NS);
            myb[q] = b;
            atomicAdd(&hcnt[b], 1);
        }
    }
    __syncthreads();
    if (tid < NBUK) {
        hbase[tid] = atomicAdd(&bcur[tid], hcnt[tid]);
        hcnt[tid] = 0;
    }
    __syncthreads();
#pragma unroll
    for (int q = 0; q < 8; ++q) {
        if (myb[q] >= 0) {
            int idx = hbase[myb[q]] + atomicAdd(&hcnt[myb[q]], 1);
            if (idx < CAP)
                bdata[(size_t)myb[q] * CAP + idx] = make_uint2((unsigned)myr[q], (unsigned)myc[q]);
        }
    }
}

// ---- Phase B: per-range (XCD-local) degree count from the bucket.
__global__ __launch_bounds__(256) void count_bucket_kernel(const uint2* __restrict__ bdata,
                                                           const int* __restrict__ bcur,
                                                           int CAP, int CH,
                                                           int* __restrict__ cnt) {
    const int b = blockIdx.x & 7;
    const int n = min(bcur[b], CAP);
    const uint2* d = bdata + (size_t)b * CAP;
    const int stride = CH * 256;
    for (int i = (blockIdx.x >> 3) * 256 + threadIdx.x; i < n; i += stride)
        atomicAdd(&cnt[d[i].y], 1);
}

// ---- Phase B: per-range fill of srcSorted (cursor pre-set to base).
__global__ __launch_bounds__(256) void fill_bucket_kernel(const uint2* __restrict__ bdata,
                                                          const int* __restrict__ bcur,
                                                          int CAP, int CH,
                                                          int* __restrict__ cursor,
                                                          int* __restrict__ srcSorted) {
    const int b = blockIdx.x & 7;
    const int n = min(bcur[b], CAP);
    const uint2* d = bdata + (size_t)b * CAP;
    const int stride = CH * 256;
    for (int i = (blockIdx.x >> 3) * 256 + threadIdx.x; i < n; i += stride) {
        uint2 rc = d[i];
        int idx = atomicAdd(&cursor[rc.y], 1);
        srcSorted[idx] = (int)rc.x;
    }
}

__global__ __launch_bounds__(256) void dinv_kernel(const int* __restrict__ cnt,
                                                   float* __restrict__ dinv, int N) {
    int i = blockIdx.x * 256 + threadIdx.x;
    if (i < N) dinv[i] = rsqrtf((float)cnt[i] + 1.0f);   // +1 self-loop
}

__global__ __launch_bounds__(256) void scan_block_kernel(const int* __restrict__ cnt,
                                                         int* __restrict__ base,
                                                         int* __restrict__ sums, int N) {
    __shared__ int s[256];
    int tid = threadIdx.x;
    int i = blockIdx.x * 256 + tid;
    int v = (i < N) ? cnt[i] : 0;
    s[tid] = v;
    __syncthreads();
#pragma unroll
    for (int d = 1; d < 256; d <<= 1) {
        int t = (tid >= d) ? s[tid - d] : 0;
        __syncthreads();
        s[tid] += t;
        __syncthreads();
    }
    if (i < N) base[i] = s[tid] - v;
    if (tid == 255) sums[blockIdx.x] = s[255];
}

__global__ __launch_bounds__(512) void scan_sums_kernel(int* __restrict__ sums, int nb) {
    __shared__ int s[512];
    int tid = threadIdx.x;
    int v = (tid < nb) ? sums[tid] : 0;
    s[tid] = v;
    __syncthreads();
#pragma unroll
    for (int d = 1; d < 512; d <<= 1) {
        int t = (tid >= d) ? s[tid - d] : 0;
        __syncthreads();
        s[tid] += t;
        __syncthreads();
    }
    if (tid < nb) sums[tid] = s[tid] - v;
}

// also initializes cursor = base (drops the d2d memcpy)
__global__ __launch_bounds__(256) void add_offsets_kernel(int* __restrict__ base,
                                                          int* __restrict__ cursor,
                                                          const int* __restrict__ sums,
                                                          const int* __restrict__ cnt, int N) {
    int i = blockIdx.x * 256 + threadIdx.x;
    if (i < N) {
        int v = base[i] + sums[i >> 8];
        base[i] = v;
        cursor[i] = v;
        if (i == N - 1) base[N] = v + cnt[i]; // = E
    }
}

// ---- W [128 x C] fp32 row-major -> WT [C x 128] fp16, k-index XOR-swizzled
__global__ __launch_bounds__(256) void wtrans_kernel(const float* __restrict__ W,
                                                     __half* __restrict__ WT, int C) {
    int idx = blockIdx.x * 256 + threadIdx.x;
    if (idx >= 128 * C) return;
    int k = idx / C, c = idx % C;
    float v = W[idx];
    WT[c * 128 + (k ^ ((c & 7) << 3))] = __float2half_rn(v);
}

// ---- fp16 MFMA GEMM + dinv-scaled epilogue:
// H[r][:] = half( dinv[r] * (X[r][:] @ W) ),  fp32 accum.
template <int COLS, typename XT>
__global__ __launch_bounds__(256) void mfma_gemm(const XT* __restrict__ X,
                                                 const __half* __restrict__ WT,
                                                 const float* __restrict__ dinv,
                                                 __half* __restrict__ H, int N) {
    __shared__ _Float16 sX[64 * 128];
    __shared__ _Float16 sW[COLS * 128];
    const int tid = threadIdx.x;
    const int row0 = blockIdx.x * 64;

    {
        const uintx4* src = (const uintx4*)WT;
        uintx4* dst = (uintx4*)sW;
        for (int i = tid; i < COLS * 16; i += 256) dst[i] = src[i];
    }
    for (int cidx = tid; cidx < 1024; cidx += 256) {
        int r = cidx >> 4, k8 = cidx & 15;
        int gr = row0 + r;
        half8 h;
#pragma unroll
        for (int q = 0; q < 8; ++q) h[q] = (_Float16)0.f;
        if (gr < N) {
            if constexpr (sizeof(XT) == 4) {
                const float4* p = (const float4*)((const float*)X + (size_t)gr * 128 + k8 * 8);
                float4 f0 = p[0], f1 = p[1];
                h[0] = (_Float16)f0.x; h[1] = (_Float16)f0.y;
                h[2] = (_Float16)f0.z; h[3] = (_Float16)f0.w;
                h[4] = (_Float16)f1.x; h[5] = (_Float16)f1.y;
                h[6] = (_Float16)f1.z; h[7] = (_Float16)f1.w;
            } else {
                h = *(const half8*)((const _Float16*)X + (size_t)gr * 128 + k8 * 8);
            }
        }
        *(half8*)(sX + r * 128 + ((k8 * 8) ^ ((r & 7) << 3))) = h;
    }
    __syncthreads();

    const int w = tid >> 6;
    const int lane = tid & 63;
    const int l15 = lane & 15, l4 = lane >> 4;
    constexpr int WCOLS = COLS / 2;
    constexpr int NCB = WCOLS / 16;
    const int wr = (w >> 1) * 32;
    const int wc = (w & 1) * WCOLS;

    half8 a[2][4];
#pragma unroll
    for (int rb = 0; rb < 2; ++rb) {
        int r = wr + rb * 16 + l15;
#pragma unroll
        for (int kb = 0; kb < 4; ++kb)
            a[rb][kb] = *(const half8*)(sX + r * 128 + ((kb * 32 + l4 * 8) ^ ((r & 7) << 3)));
    }

    floatx4 acc[2][NCB];
#pragma unroll
    for (int rb = 0; rb < 2; ++rb)
#pragma unroll
        for (int cb = 0; cb < NCB; ++cb) acc[rb][cb] = (floatx4)(0.f);

#pragma unroll
    for (int cb = 0; cb < NCB; ++cb) {
        int c = wc + cb * 16 + l15;
#pragma unroll
        for (int kb = 0; kb < 4; ++kb) {
            half8 b = *(const half8*)(sW + c * 128 + ((kb * 32 + l4 * 8) ^ ((c & 7) << 3)));
#pragma unroll
            for (int rb = 0; rb < 2; ++rb)
                acc[rb][cb] = __builtin_amdgcn_mfma_f32_16x16x32_f16(a[rb][kb], b, acc[rb][cb], 0, 0, 0);
        }
    }

#pragma unroll
    for (int rb = 0; rb < 2; ++rb) {
        float dv[4];
#pragma unroll
        for (int r = 0; r < 4; ++r) {
            int gr = row0 + wr + rb * 16 + l4 * 4 + r;
            dv[r] = (gr < N) ? dinv[gr] : 0.f;
        }
#pragma unroll
        for (int cb = 0; cb < NCB; ++cb)
#pragma unroll
            for (int r = 0; r < 4; ++r) {
                int gr = row0 + wr + rb * 16 + l4 * 4 + r;
                if (gr < N) {
                    int gc = wc + cb * 16 + l15;
                    H[(size_t)gr * COLS + gc] = __float2half_rn(acc[rb][cb][r] * dv[r]);
                }
            }
    }
}

__device__ inline void add8(float (&a)[8], uintx4 v) {
    union { uintx4 u; __half2 h[4]; } cv;
    cv.u = v;
#pragma unroll
    for (int q = 0; q < 4; ++q) {
        a[2 * q]     += __low2float(cv.h[q]);
        a[2 * q + 1] += __high2float(cv.h[q]);
    }
}

// ---- Pull aggregation over pre-scaled H': out[n] = dn*(sum H'[s] + H'[n]) + b
template <int C, bool RELU, typename OT>
__global__ __launch_bounds__(256) void agg_kernel(const __half* __restrict__ H16,
                                                  const int* __restrict__ srcSorted,
                                                  const int* __restrict__ base,
                                                  const float* __restrict__ dinv,
                                                  const float* __restrict__ b,
                                                  OT* __restrict__ out, int N) {
    constexpr int G = C / 8;
    constexpr int NPB = 256 / G;
    const int lane = threadIdx.x % G;
    const int sub = threadIdx.x / G;
    const int n = blockIdx.x * NPB + sub;
    if (n >= N) return;

    const uintx4* H4 = (const uintx4*)H16;
    const int s = base[n];
    const int e = base[n + 1];

    float acc[8];
#pragma unroll
    for (int q = 0; q < 8; ++q) acc[q] = 0.f;

    int i = s;
    for (; i + 3 < e; i += 4) {
        int s0 = srcSorted[i], s1 = srcSorted[i + 1];
        int s2 = srcSorted[i + 2], s3 = srcSorted[i + 3];
        uintx4 v0 = H4[(size_t)s0 * G + lane];
        uintx4 v1 = H4[(size_t)s1 * G + lane];
        uintx4 v2 = H4[(size_t)s2 * G + lane];
        uintx4 v3 = H4[(size_t)s3 * G + lane];
        add8(acc, v0);
        add8(acc, v1);
        add8(acc, v2);
        add8(acc, v3);
    }
    for (; i < e; ++i) {
        int s0 = srcSorted[i];
        add8(acc, H4[(size_t)s0 * G + lane]);
    }

    const float dn = dinv[n];
    uintx4 hv = H4[(size_t)n * G + lane];
    union { uintx4 u; __half2 h[4]; } cv;
    cv.u = hv;
    float o[8];
#pragma unroll
    for (int q = 0; q < 4; ++q) {
        o[2 * q]     = dn * (acc[2 * q]     + __low2float(cv.h[q]));
        o[2 * q + 1] = dn * (acc[2 * q + 1] + __high2float(cv.h[q]));
    }
    const float4 bb0 = ((const float4*)b)[lane * 2];
    const float4 bb1 = ((const float4*)b)[lane * 2 + 1];
    o[0] += bb0.x; o[1] += bb0.y; o[2] += bb0.z; o[3] += bb0.w;
    o[4] += bb1.x; o[5] += bb1.y; o[6] += bb1.z; o[7] += bb1.w;
    if (RELU) {
#pragma unroll
        for (int q = 0; q < 8; ++q) o[q] = fmaxf(o[q], 0.f);
    }
    if constexpr (sizeof(OT) == 2) {
        half8 st;
#pragma unroll
        for (int q = 0; q < 8; ++q) st[q] = (_Float16)o[q];
        *(half8*)((_Float16*)out + (size_t)n * C + lane * 8) = st;
    } else {
        float4* op = (float4*)((float*)out + (size_t)n * C + lane * 8);
        op[0] = make_float4(o[0], o[1], o[2], o[3]);
        op[1] = make_float4(o[4], o[5], o[6], o[7]);
    }
}

static inline int cdiv(long long a, long long b) { return (int)((a + b - 1) / b); }

extern "C" void kernel_launch(void* const* d_in, const int* in_sizes, int n_in,
                              void* d_out, int out_size, void* d_ws, size_t ws_size,
                              hipStream_t stream) {
    const float* x  = (const float*)d_in[0];
    const float* W1 = (const float*)d_in[1];
    const float* b1 = (const float*)d_in[2];
    const float* W2 = (const float*)d_in[3];
    const float* b2 = (const float*)d_in[4];
    const int*   ei = (const int*)d_in[5];

    const int N = in_sizes[0] / 128;   // 100000
    const int E = in_sizes[5] / 2;     // 1600000
    const int* rows = ei;              // edge_index[0] = source
    const int* cols = ei + E;          // edge_index[1] = target

    const int nbN = cdiv(N, 256);      // 391
    const int NS = cdiv(N, 8);         // 12500 nodes per range
    const int CAP = E / 8 + E / 64;    // 225000 per bucket (>>50 sigma margin)
    const int CH = 96;                 // blocks per range for phase B

    char* ws = (char*)d_ws;
    size_t off = 0;
    auto alloc = [&](size_t bytes) {
        size_t p = off;
        off = (off + bytes + 255) & ~(size_t)255;
        return p;
    };
    int*      cnt    = (int*)(ws + alloc((size_t)N * 4));
    int*      cursor = (int*)(ws + alloc((size_t)(N + 1) * 4));
    int*      base   = (int*)(ws + alloc((size_t)(N + 1) * 4));
    int*      sums   = (int*)(ws + alloc((size_t)512 * 4));
    int*      bcur   = (int*)(ws + alloc((size_t)NBUK * 4));
    float*    dinv   = (float*)(ws + alloc((size_t)N * 4));
    int*      srcS   = (int*)(ws + alloc((size_t)E * 4));
    uint2*    bdata  = (uint2*)(ws + alloc((size_t)NBUK * CAP * 8));
    __half*   WT1    = (__half*)(ws + alloc((size_t)128 * 128 * 2));
    __half*   WT2    = (__half*)(ws + alloc((size_t)128 * 64 * 2));
    __half*   H16    = (__half*)(ws + alloc((size_t)N * 128 * 2));  // h1', then h2'
    __half*   X2h    = (__half*)(ws + alloc((size_t)N * 128 * 2));  // relu'd layer-1
    (void)ws_size;

    float* OUT = (float*)d_out;

    // --- CSR by destination + dinv (shared by both layers) ---
    hipMemsetAsync(cnt, 0, (size_t)N * 4, stream);
    hipMemsetAsync(bcur, 0, (size_t)NBUK * 4, stream);
    bucket_kernel<<<cdiv(E, 2048), 256, 0, stream>>>(rows, cols, E, NS, CAP, bcur, bdata);
    count_bucket_kernel<<<8 * CH, 256, 0, stream>>>(bdata, bcur, CAP, CH, cnt);
    dinv_kernel<<<nbN, 256, 0, stream>>>(cnt, dinv, N);
    scan_block_kernel<<<nbN, 256, 0, stream>>>(cnt, base, sums, N);
    scan_sums_kernel<<<1, 512, 0, stream>>>(sums, nbN);
    add_offsets_kernel<<<nbN, 256, 0, stream>>>(base, cursor, sums, cnt, N);
    fill_bucket_kernel<<<8 * CH, 256, 0, stream>>>(bdata, bcur, CAP, CH, cursor, srcS);

    // --- weight prep (fp16, transposed, swizzled) ---
    wtrans_kernel<<<cdiv(128 * 128, 256), 256, 0, stream>>>(W1, WT1, 128);
    wtrans_kernel<<<cdiv(128 * 64, 256), 256, 0, stream>>>(W2, WT2, 64);

    // --- layer 1 ---
    mfma_gemm<128, float><<<cdiv(N, 64), 256, 0, stream>>>(x, WT1, dinv, H16, N);
    agg_kernel<128, true, __half><<<cdiv(N, 16), 256, 0, stream>>>(H16, srcS, base, dinv, b1, X2h, N);

    // --- layer 2 ---
    mfma_gemm<64, _Float16><<<cdiv(N, 64), 256, 0, stream>>>((const _Float16*)X2h, WT2, dinv, H16, N);
    agg_kernel<64, false, float><<<cdiv(N, 32), 256, 0, stream>>>(H16, srcS, base, dinv, b2, OUT, N);
}

// Round 7
// 283.903 us; speedup vs baseline: 1.4102x; 1.3781x over previous
//
#include <hip/hip_runtime.h>
#include <hip/hip_fp16.h>

typedef _Float16 half8 __attribute__((ext_vector_type(8)));
typedef float floatx4 __attribute__((ext_vector_type(4)));
typedef unsigned int uintx4 __attribute__((ext_vector_type(4)));

// ---------------------------------------------------------------------------
// GCN 2-layer, pull-style. R7: CSR build via 128 fine buckets + per-bucket LDS
// counting sort (srcSorted written once, full lines). dinv folded into GEMM.
//   H1' = dinv .* (x@W1)  [fp16]
//   x2  = relu( dn*(sum H1'[s] + H1'[n]) + b1 )  [fp16]
//   H2' = dinv .* (x2@W2) [fp16] ; out = dn*(sum H2'[s] + H2'[n]) + b2 [fp32]
// ---------------------------------------------------------------------------

#define NBUK 128
#define CAPB 16384   // per-bucket capacity (avg 12.5K, ~34 sigma headroom)

// ---- Phase A: one pass over edges; partition into 128 destination buckets.
// ---- Packed entry: (col_local << 17) | row   (row < 2^17, col_local < 1024)
__global__ __launch_bounds__(256) void bucket_kernel(const int* __restrict__ rows,
                                                     const int* __restrict__ cols,
                                                     int E, int NSUB,
                                                     int* __restrict__ bcur,
                                                     unsigned* __restrict__ bdata) {
    __shared__ int hcnt[NBUK];
    __shared__ int hbase[NBUK];
    const int tid = threadIdx.x;
    const int chunk0 = blockIdx.x * 2048;
    if (tid < NBUK) hcnt[tid] = 0;
    __syncthreads();
    unsigned up[8];
    int ub[8];
#pragma unroll
    for (int q = 0; q < 8; ++q) {
        int e = chunk0 + q * 256 + tid;
        ub[q] = -1;
        if (e < E) {
            unsigned r = (unsigned)rows[e];
            unsigned c = (unsigned)cols[e];
            int b = (int)(c / (unsigned)NSUB);
            unsigned lc = c - (unsigned)b * (unsigned)NSUB;
            ub[q] = b;
            up[q] = r | (lc << 17);
            atomicAdd(&hcnt[b], 1);
        }
    }
    __syncthreads();
    if (tid < NBUK) {
        hbase[tid] = atomicAdd(&bcur[tid], hcnt[tid]);
        hcnt[tid] = 0;
    }
    __syncthreads();
#pragma unroll
    for (int q = 0; q < 8; ++q) {
        if (ub[q] >= 0) {
            int idx = hbase[ub[q]] + atomicAdd(&hcnt[ub[q]], 1);
            if (idx < CAPB) bdata[(size_t)ub[q] * CAPB + idx] = up[q];
        }
    }
}

// ---- Exclusive scan of the 128 bucket sizes; also writes base[N].
__global__ __launch_bounds__(128) void exscan_bucket_kernel(const int* __restrict__ bcur,
                                                            int* __restrict__ bbase,
                                                            int N, int* __restrict__ baseOut) {
    __shared__ int s[NBUK];
    int tid = threadIdx.x;
    int v = min(bcur[tid], CAPB);
    s[tid] = v;
    __syncthreads();
    for (int d = 1; d < NBUK; d <<= 1) {
        int t = (tid >= d) ? s[tid - d] : 0;
        __syncthreads();
        s[tid] += t;
        __syncthreads();
    }
    bbase[tid] = s[tid] - v;
    if (tid == NBUK - 1) baseOut[N] = s[tid];   // = E (absent overflow)
}

// ---- Phase C: one block per bucket. LDS histogram -> scan (emit base/dinv)
// ---- -> LDS scatter -> coalesced full-line stream-out of srcSorted segment.
__global__ __launch_bounds__(256) void sortfill_kernel(const unsigned* __restrict__ bdata,
                                                       const int* __restrict__ bcur,
                                                       const int* __restrict__ bbase,
                                                       int NSUB, int N,
                                                       int* __restrict__ baseOut,
                                                       float* __restrict__ dinvOut,
                                                       int* __restrict__ srcSorted) {
    __shared__ int cnt[1024];
    __shared__ int cur[1024];
    __shared__ int wsum[4];
    __shared__ int srcOut[CAPB];
    const int tid = threadIdx.x;
    const int b = blockIdx.x;
    const int nb = min(bcur[b], CAPB);
    const int base0 = bbase[b];
    const int n0 = b * NSUB;
    const int nn = min(NSUB, N - n0);
    const unsigned* bd = bdata + (size_t)b * CAPB;

    for (int i = tid; i < 1024; i += 256) cnt[i] = 0;
    __syncthreads();
    // pass 1: histogram over local destinations
    for (int i = tid; i < nb; i += 256) atomicAdd(&cnt[bd[i] >> 17], 1);
    __syncthreads();
    // block exclusive scan over 1024 (4 elems/thread)
    int a0 = cnt[4 * tid], a1 = cnt[4 * tid + 1], a2 = cnt[4 * tid + 2], a3 = cnt[4 * tid + 3];
    int s0 = a0, s1 = s0 + a1, s2 = s1 + a2, s3 = s2 + a3;
    int tot = s3;
    const int lane = tid & 63, wid = tid >> 6;
    for (int off = 1; off < 64; off <<= 1) {
        int u = __shfl_up(tot, off, 64);
        if (lane >= off) tot += u;
    }
    if (lane == 63) wsum[wid] = tot;
    __syncthreads();
    int woff = 0;
#pragma unroll
    for (int w = 0; w < 4; ++w)
        if (w < wid) woff += wsum[w];
    const int tbase = woff + tot - s3;      // exclusive base of this thread's 4
    cur[4 * tid]     = tbase;
    cur[4 * tid + 1] = tbase + s0;
    cur[4 * tid + 2] = tbase + s1;
    cur[4 * tid + 3] = tbase + s2;
    __syncthreads();
    // emit global base + dinv for this bucket's nodes
    for (int i = tid; i < nn; i += 256) {
        baseOut[n0 + i] = base0 + cur[i];
        dinvOut[n0 + i] = rsqrtf((float)cnt[i] + 1.0f);
    }
    __syncthreads();
    // pass 2: scatter rows into LDS by destination
    for (int i = tid; i < nb; i += 256) {
        unsigned u = bd[i];
        int c = (int)(u >> 17);
        int p = atomicAdd(&cur[c], 1);
        srcOut[p] = (int)(u & 0x1FFFFu);
    }
    __syncthreads();
    // stream out, full lines, written once
    for (int i = tid; i < nb; i += 256) srcSorted[base0 + i] = srcOut[i];
}

// ---- W [128 x C] fp32 row-major -> WT [C x 128] fp16, k-index XOR-swizzled
__global__ __launch_bounds__(256) void wtrans_kernel(const float* __restrict__ W,
                                                     __half* __restrict__ WT, int C) {
    int idx = blockIdx.x * 256 + threadIdx.x;
    if (idx >= 128 * C) return;
    int k = idx / C, c = idx % C;
    float v = W[idx];
    WT[c * 128 + (k ^ ((c & 7) << 3))] = __float2half_rn(v);
}

// ---- fp16 MFMA GEMM + dinv-scaled epilogue:
// H[r][:] = half( dinv[r] * (X[r][:] @ W) ),  fp32 accum.
template <int COLS, typename XT>
__global__ __launch_bounds__(256) void mfma_gemm(const XT* __restrict__ X,
                                                 const __half* __restrict__ WT,
                                                 const float* __restrict__ dinv,
                                                 __half* __restrict__ H, int N) {
    __shared__ _Float16 sX[64 * 128];
    __shared__ _Float16 sW[COLS * 128];
    const int tid = threadIdx.x;
    const int row0 = blockIdx.x * 64;

    {
        const uintx4* src = (const uintx4*)WT;
        uintx4* dst = (uintx4*)sW;
        for (int i = tid; i < COLS * 16; i += 256) dst[i] = src[i];
    }
    for (int cidx = tid; cidx < 1024; cidx += 256) {
        int r = cidx >> 4, k8 = cidx & 15;
        int gr = row0 + r;
        half8 h;
#pragma unroll
        for (int q = 0; q < 8; ++q) h[q] = (_Float16)0.f;
        if (gr < N) {
            if constexpr (sizeof(XT) == 4) {
                const float4* p = (const float4*)((const float*)X + (size_t)gr * 128 + k8 * 8);
                float4 f0 = p[0], f1 = p[1];
                h[0] = (_Float16)f0.x; h[1] = (_Float16)f0.y;
                h[2] = (_Float16)f0.z; h[3] = (_Float16)f0.w;
                h[4] = (_Float16)f1.x; h[5] = (_Float16)f1.y;
                h[6] = (_Float16)f1.z; h[7] = (_Float16)f1.w;
            } else {
                h = *(const half8*)((const _Float16*)X + (size_t)gr * 128 + k8 * 8);
            }
        }
        *(half8*)(sX + r * 128 + ((k8 * 8) ^ ((r & 7) << 3))) = h;
    }
    __syncthreads();

    const int w = tid >> 6;
    const int lane = tid & 63;
    const int l15 = lane & 15, l4 = lane >> 4;
    constexpr int WCOLS = COLS / 2;
    constexpr int NCB = WCOLS / 16;
    const int wr = (w >> 1) * 32;
    const int wc = (w & 1) * WCOLS;

    half8 a[2][4];
#pragma unroll
    for (int rb = 0; rb < 2; ++rb) {
        int r = wr + rb * 16 + l15;
#pragma unroll
        for (int kb = 0; kb < 4; ++kb)
            a[rb][kb] = *(const half8*)(sX + r * 128 + ((kb * 32 + l4 * 8) ^ ((r & 7) << 3)));
    }

    floatx4 acc[2][NCB];
#pragma unroll
    for (int rb = 0; rb < 2; ++rb)
#pragma unroll
        for (int cb = 0; cb < NCB; ++cb) acc[rb][cb] = (floatx4)(0.f);

#pragma unroll
    for (int cb = 0; cb < NCB; ++cb) {
        int c = wc + cb * 16 + l15;
#pragma unroll
        for (int kb = 0; kb < 4; ++kb) {
            half8 b = *(const half8*)(sW + c * 128 + ((kb * 32 + l4 * 8) ^ ((c & 7) << 3)));
#pragma unroll
            for (int rb = 0; rb < 2; ++rb)
                acc[rb][cb] = __builtin_amdgcn_mfma_f32_16x16x32_f16(a[rb][kb], b, acc[rb][cb], 0, 0, 0);
        }
    }

#pragma unroll
    for (int rb = 0; rb < 2; ++rb) {
        float dv[4];
#pragma unroll
        for (int r = 0; r < 4; ++r) {
            int gr = row0 + wr + rb * 16 + l4 * 4 + r;
            dv[r] = (gr < N) ? dinv[gr] : 0.f;
        }
#pragma unroll
        for (int cb = 0; cb < NCB; ++cb)
#pragma unroll
            for (int r = 0; r < 4; ++r) {
                int gr = row0 + wr + rb * 16 + l4 * 4 + r;
                if (gr < N) {
                    int gc = wc + cb * 16 + l15;
                    H[(size_t)gr * COLS + gc] = __float2half_rn(acc[rb][cb][r] * dv[r]);
                }
            }
    }
}

__device__ inline void add8(float (&a)[8], uintx4 v) {
    union { uintx4 u; __half2 h[4]; } cv;
    cv.u = v;
#pragma unroll
    for (int q = 0; q < 4; ++q) {
        a[2 * q]     += __low2float(cv.h[q]);
        a[2 * q + 1] += __high2float(cv.h[q]);
    }
}

// ---- Pull aggregation over pre-scaled H': out[n] = dn*(sum H'[s] + H'[n]) + b
template <int C, bool RELU, typename OT>
__global__ __launch_bounds__(256) void agg_kernel(const __half* __restrict__ H16,
                                                  const int* __restrict__ srcSorted,
                                                  const int* __restrict__ base,
                                                  const float* __restrict__ dinv,
                                                  const float* __restrict__ b,
                                                  OT* __restrict__ out, int N) {
    constexpr int G = C / 8;
    constexpr int NPB = 256 / G;
    const int lane = threadIdx.x % G;
    const int sub = threadIdx.x / G;
    const int n = blockIdx.x * NPB + sub;
    if (n >= N) return;

    const uintx4* H4 = (const uintx4*)H16;
    const int s = base[n];
    const int e = base[n + 1];

    float acc[8];
#pragma unroll
    for (int q = 0; q < 8; ++q) acc[q] = 0.f;

    int i = s;
    for (; i + 3 < e; i += 4) {
        int s0 = srcSorted[i], s1 = srcSorted[i + 1];
        int s2 = srcSorted[i + 2], s3 = srcSorted[i + 3];
        uintx4 v0 = H4[(size_t)s0 * G + lane];
        uintx4 v1 = H4[(size_t)s1 * G + lane];
        uintx4 v2 = H4[(size_t)s2 * G + lane];
        uintx4 v3 = H4[(size_t)s3 * G + lane];
        add8(acc, v0);
        add8(acc, v1);
        add8(acc, v2);
        add8(acc, v3);
    }
    for (; i < e; ++i) {
        int s0 = srcSorted[i];
        add8(acc, H4[(size_t)s0 * G + lane]);
    }

    const float dn = dinv[n];
    uintx4 hv = H4[(size_t)n * G + lane];
    union { uintx4 u; __half2 h[4]; } cv;
    cv.u = hv;
    float o[8];
#pragma unroll
    for (int q = 0; q < 4; ++q) {
        o[2 * q]     = dn * (acc[2 * q]     + __low2float(cv.h[q]));
        o[2 * q + 1] = dn * (acc[2 * q + 1] + __high2float(cv.h[q]));
    }
    const float4 bb0 = ((const float4*)b)[lane * 2];
    const float4 bb1 = ((const float4*)b)[lane * 2 + 1];
    o[0] += bb0.x; o[1] += bb0.y; o[2] += bb0.z; o[3] += bb0.w;
    o[4] += bb1.x; o[5] += bb1.y; o[6] += bb1.z; o[7] += bb1.w;
    if (RELU) {
#pragma unroll
        for (int q = 0; q < 8; ++q) o[q] = fmaxf(o[q], 0.f);
    }
    if constexpr (sizeof(OT) == 2) {
        half8 st;
#pragma unroll
        for (int q = 0; q < 8; ++q) st[q] = (_Float16)o[q];
        *(half8*)((_Float16*)out + (size_t)n * C + lane * 8) = st;
    } else {
        float4* op = (float4*)((float*)out + (size_t)n * C + lane * 8);
        op[0] = make_float4(o[0], o[1], o[2], o[3]);
        op[1] = make_float4(o[4], o[5], o[6], o[7]);
    }
}

static inline int cdiv(long long a, long long b) { return (int)((a + b - 1) / b); }

extern "C" void kernel_launch(void* const* d_in, const int* in_sizes, int n_in,
                              void* d_out, int out_size, void* d_ws, size_t ws_size,
                              hipStream_t stream) {
    const float* x  = (const float*)d_in[0];
    const float* W1 = (const float*)d_in[1];
    const float* b1 = (const float*)d_in[2];
    const float* W2 = (const float*)d_in[3];
    const float* b2 = (const float*)d_in[4];
    const int*   ei = (const int*)d_in[5];

    const int N = in_sizes[0] / 128;   // 100000
    const int E = in_sizes[5] / 2;     // 1600000
    const int* rows = ei;              // edge_index[0] = source
    const int* cols = ei + E;          // edge_index[1] = target

    const int NSUB = cdiv(N, NBUK);    // 782 nodes per bucket

    char* ws = (char*)d_ws;
    size_t off = 0;
    auto alloc = [&](size_t bytes) {
        size_t p = off;
        off = (off + bytes + 255) & ~(size_t)255;
        return p;
    };
    int*      bcur  = (int*)(ws + alloc((size_t)NBUK * 4));
    int*      bbase = (int*)(ws + alloc((size_t)NBUK * 4));
    int*      base  = (int*)(ws + alloc((size_t)(N + 1) * 4));
    float*    dinv  = (float*)(ws + alloc((size_t)N * 4));
    int*      srcS  = (int*)(ws + alloc((size_t)E * 4));
    unsigned* bdata = (unsigned*)(ws + alloc((size_t)NBUK * CAPB * 4));
    __half*   WT1   = (__half*)(ws + alloc((size_t)128 * 128 * 2));
    __half*   WT2   = (__half*)(ws + alloc((size_t)128 * 64 * 2));
    __half*   H16   = (__half*)(ws + alloc((size_t)N * 128 * 2));  // h1', then h2'
    __half*   X2h   = (__half*)(ws + alloc((size_t)N * 128 * 2));  // relu'd layer-1
    (void)ws_size;

    float* OUT = (float*)d_out;

    // --- CSR by destination + dinv (shared by both layers) ---
    hipMemsetAsync(bcur, 0, (size_t)NBUK * 4, stream);
    bucket_kernel<<<cdiv(E, 2048), 256, 0, stream>>>(rows, cols, E, NSUB, bcur, bdata);
    exscan_bucket_kernel<<<1, NBUK, 0, stream>>>(bcur, bbase, N, base);
    sortfill_kernel<<<NBUK, 256, 0, stream>>>(bdata, bcur, bbase, NSUB, N, base, dinv, srcS);

    // --- weight prep (fp16, transposed, swizzled) ---
    wtrans_kernel<<<cdiv(128 * 128, 256), 256, 0, stream>>>(W1, WT1, 128);
    wtrans_kernel<<<cdiv(128 * 64, 256), 256, 0, stream>>>(W2, WT2, 64);

    // --- layer 1 ---
    mfma_gemm<128, float><<<cdiv(N, 64), 256, 0, stream>>>(x, WT1, dinv, H16, N);
    agg_kernel<128, true, __half><<<cdiv(N, 16), 256, 0, stream>>>(H16, srcS, base, dinv, b1, X2h, N);

    // --- layer 2 ---
    mfma_gemm<64, _Float16><<<cdiv(N, 64), 256, 0, stream>>>((const _Float16*)X2h, WT2, dinv, H16, N);
    agg_kernel<64, false, float><<<cdiv(N, 32), 256, 0, stream>>>(H16, srcS, base, dinv, b2, OUT, N);
}

// Round 8
// 278.118 us; speedup vs baseline: 1.4395x; 1.0208x over previous
//
#include <hip/hip_runtime.h>
#include <hip/hip_fp16.h>

typedef _Float16 half8 __attribute__((ext_vector_type(8)));
typedef float floatx4 __attribute__((ext_vector_type(4)));
typedef unsigned int uintx4 __attribute__((ext_vector_type(4)));

// ---------------------------------------------------------------------------
// GCN 2-layer, pull-style. R8: fused agg1+gemm2 (x2 tile never leaves LDS),
// 8-deep gather unroll, padded bucket counters.
//   H1' = dinv .* (x@W1)                                   [mfma_gemm, fp16]
//   x2  = relu(dn*(sum H1'[s] + H1'[n]) + b1) ; H2' = dinv .* (x2@W2)
//                                                      [fused agg_gemm, fp16]
//   out = dn*(sum H2'[s] + H2'[n]) + b2                    [agg_kernel, fp32]
// ---------------------------------------------------------------------------

#define NBUK 128
#define CAPB 16384   // per-bucket capacity (avg 12.5K, ~34 sigma headroom)
#define BPAD 16      // bcur padding stride (one counter per 64B line)

// ---- Phase A: one pass over edges; partition into 128 destination buckets.
// ---- Packed entry: (col_local << 17) | row
__global__ __launch_bounds__(256) void bucket_kernel(const int* __restrict__ rows,
                                                     const int* __restrict__ cols,
                                                     int E, int NSUB,
                                                     int* __restrict__ bcur,
                                                     unsigned* __restrict__ bdata) {
    __shared__ int hcnt[NBUK];
    __shared__ int hbase[NBUK];
    const int tid = threadIdx.x;
    const int chunk0 = blockIdx.x * 4096;
    if (tid < NBUK) hcnt[tid] = 0;
    __syncthreads();
    unsigned up[16];
    int ub[16];
#pragma unroll
    for (int q = 0; q < 16; ++q) {
        int e = chunk0 + q * 256 + tid;
        ub[q] = -1;
        if (e < E) {
            unsigned r = (unsigned)rows[e];
            unsigned c = (unsigned)cols[e];
            int b = (int)(c / (unsigned)NSUB);
            unsigned lc = c - (unsigned)b * (unsigned)NSUB;
            ub[q] = b;
            up[q] = r | (lc << 17);
            atomicAdd(&hcnt[b], 1);
        }
    }
    __syncthreads();
    if (tid < NBUK) {
        hbase[tid] = atomicAdd(&bcur[tid * BPAD], hcnt[tid]);
        hcnt[tid] = 0;
    }
    __syncthreads();
#pragma unroll
    for (int q = 0; q < 16; ++q) {
        if (ub[q] >= 0) {
            int idx = hbase[ub[q]] + atomicAdd(&hcnt[ub[q]], 1);
            if (idx < CAPB) bdata[(size_t)ub[q] * CAPB + idx] = up[q];
        }
    }
}

// ---- Exclusive scan of the 128 bucket sizes; also writes base[N].
__global__ __launch_bounds__(128) void exscan_bucket_kernel(const int* __restrict__ bcur,
                                                            int* __restrict__ bbase,
                                                            int N, int* __restrict__ baseOut) {
    __shared__ int s[NBUK];
    int tid = threadIdx.x;
    int v = min(bcur[tid * BPAD], CAPB);
    s[tid] = v;
    __syncthreads();
    for (int d = 1; d < NBUK; d <<= 1) {
        int t = (tid >= d) ? s[tid - d] : 0;
        __syncthreads();
        s[tid] += t;
        __syncthreads();
    }
    bbase[tid] = s[tid] - v;
    if (tid == NBUK - 1) baseOut[N] = s[tid];   // = E
}

// ---- Phase C: one block per bucket. LDS histogram -> scan (emit base/dinv)
// ---- -> LDS scatter -> coalesced full-line stream-out of srcSorted segment.
__global__ __launch_bounds__(256) void sortfill_kernel(const unsigned* __restrict__ bdata,
                                                       const int* __restrict__ bcur,
                                                       const int* __restrict__ bbase,
                                                       int NSUB, int N,
                                                       int* __restrict__ baseOut,
                                                       float* __restrict__ dinvOut,
                                                       int* __restrict__ srcSorted) {
    __shared__ int cnt[1024];
    __shared__ int cur[1024];
    __shared__ int wsum[4];
    __shared__ int srcOut[CAPB];
    const int tid = threadIdx.x;
    const int b = blockIdx.x;
    const int nb = min(bcur[b * BPAD], CAPB);
    const int base0 = bbase[b];
    const int n0 = b * NSUB;
    const int nn = min(NSUB, N - n0);
    const unsigned* bd = bdata + (size_t)b * CAPB;

    for (int i = tid; i < 1024; i += 256) cnt[i] = 0;
    __syncthreads();
    for (int i = tid; i < nb; i += 256) atomicAdd(&cnt[bd[i] >> 17], 1);
    __syncthreads();
    int a0 = cnt[4 * tid], a1 = cnt[4 * tid + 1], a2 = cnt[4 * tid + 2], a3 = cnt[4 * tid + 3];
    int s0 = a0, s1 = s0 + a1, s2 = s1 + a2, s3 = s2 + a3;
    int tot = s3;
    const int lane = tid & 63, wid = tid >> 6;
    for (int off = 1; off < 64; off <<= 1) {
        int u = __shfl_up(tot, off, 64);
        if (lane >= off) tot += u;
    }
    if (lane == 63) wsum[wid] = tot;
    __syncthreads();
    int woff = 0;
#pragma unroll
    for (int w = 0; w < 4; ++w)
        if (w < wid) woff += wsum[w];
    const int tbase = woff + tot - s3;
    cur[4 * tid]     = tbase;
    cur[4 * tid + 1] = tbase + s0;
    cur[4 * tid + 2] = tbase + s1;
    cur[4 * tid + 3] = tbase + s2;
    __syncthreads();
    for (int i = tid; i < nn; i += 256) {
        baseOut[n0 + i] = base0 + cur[i];
        dinvOut[n0 + i] = rsqrtf((float)cnt[i] + 1.0f);
    }
    __syncthreads();
    for (int i = tid; i < nb; i += 256) {
        unsigned u = bd[i];
        int c = (int)(u >> 17);
        int p = atomicAdd(&cur[c], 1);
        srcOut[p] = (int)(u & 0x1FFFFu);
    }
    __syncthreads();
    for (int i = tid; i < nb; i += 256) srcSorted[base0 + i] = srcOut[i];
}

// ---- W [128 x C] fp32 row-major -> WT [C x 128] fp16, k-index XOR-swizzled
__global__ __launch_bounds__(256) void wtrans_kernel(const float* __restrict__ W,
                                                     __half* __restrict__ WT, int C) {
    int idx = blockIdx.x * 256 + threadIdx.x;
    if (idx >= 128 * C) return;
    int k = idx / C, c = idx % C;
    float v = W[idx];
    WT[c * 128 + (k ^ ((c & 7) << 3))] = __float2half_rn(v);
}

// ---- fp16 MFMA GEMM + dinv epilogue: H[r][:] = half(dinv[r] * (X[r][:] @ W))
template <int COLS, typename XT>
__global__ __launch_bounds__(256) void mfma_gemm(const XT* __restrict__ X,
                                                 const __half* __restrict__ WT,
                                                 const float* __restrict__ dinv,
                                                 __half* __restrict__ H, int N) {
    __shared__ _Float16 sX[64 * 128];
    __shared__ _Float16 sW[COLS * 128];
    const int tid = threadIdx.x;
    const int row0 = blockIdx.x * 64;

    {
        const uintx4* src = (const uintx4*)WT;
        uintx4* dst = (uintx4*)sW;
        for (int i = tid; i < COLS * 16; i += 256) dst[i] = src[i];
    }
    for (int cidx = tid; cidx < 1024; cidx += 256) {
        int r = cidx >> 4, k8 = cidx & 15;
        int gr = row0 + r;
        half8 h;
#pragma unroll
        for (int q = 0; q < 8; ++q) h[q] = (_Float16)0.f;
        if (gr < N) {
            if constexpr (sizeof(XT) == 4) {
                const float4* p = (const float4*)((const float*)X + (size_t)gr * 128 + k8 * 8);
                float4 f0 = p[0], f1 = p[1];
                h[0] = (_Float16)f0.x; h[1] = (_Float16)f0.y;
                h[2] = (_Float16)f0.z; h[3] = (_Float16)f0.w;
                h[4] = (_Float16)f1.x; h[5] = (_Float16)f1.y;
                h[6] = (_Float16)f1.z; h[7] = (_Float16)f1.w;
            } else {
                h = *(const half8*)((const _Float16*)X + (size_t)gr * 128 + k8 * 8);
            }
        }
        *(half8*)(sX + r * 128 + ((k8 * 8) ^ ((r & 7) << 3))) = h;
    }
    __syncthreads();

    const int w = tid >> 6;
    const int lane = tid & 63;
    const int l15 = lane & 15, l4 = lane >> 4;
    constexpr int WCOLS = COLS / 2;
    constexpr int NCB = WCOLS / 16;
    const int wr = (w >> 1) * 32;
    const int wc = (w & 1) * WCOLS;

    half8 a[2][4];
#pragma unroll
    for (int rb = 0; rb < 2; ++rb) {
        int r = wr + rb * 16 + l15;
#pragma unroll
        for (int kb = 0; kb < 4; ++kb)
            a[rb][kb] = *(const half8*)(sX + r * 128 + ((kb * 32 + l4 * 8) ^ ((r & 7) << 3)));
    }

    floatx4 acc[2][NCB];
#pragma unroll
    for (int rb = 0; rb < 2; ++rb)
#pragma unroll
        for (int cb = 0; cb < NCB; ++cb) acc[rb][cb] = (floatx4)(0.f);

#pragma unroll
    for (int cb = 0; cb < NCB; ++cb) {
        int c = wc + cb * 16 + l15;
#pragma unroll
        for (int kb = 0; kb < 4; ++kb) {
            half8 b = *(const half8*)(sW + c * 128 + ((kb * 32 + l4 * 8) ^ ((c & 7) << 3)));
#pragma unroll
            for (int rb = 0; rb < 2; ++rb)
                acc[rb][cb] = __builtin_amdgcn_mfma_f32_16x16x32_f16(a[rb][kb], b, acc[rb][cb], 0, 0, 0);
        }
    }

#pragma unroll
    for (int rb = 0; rb < 2; ++rb) {
        float dv[4];
#pragma unroll
        for (int r = 0; r < 4; ++r) {
            int gr = row0 + wr + rb * 16 + l4 * 4 + r;
            dv[r] = (gr < N) ? dinv[gr] : 0.f;
        }
#pragma unroll
        for (int cb = 0; cb < NCB; ++cb)
#pragma unroll
            for (int r = 0; r < 4; ++r) {
                int gr = row0 + wr + rb * 16 + l4 * 4 + r;
                if (gr < N) {
                    int gc = wc + cb * 16 + l15;
                    H[(size_t)gr * COLS + gc] = __float2half_rn(acc[rb][cb][r] * dv[r]);
                }
            }
    }
}

__device__ inline void add8(float (&a)[8], uintx4 v) {
    union { uintx4 u; __half2 h[4]; } cv;
    cv.u = v;
#pragma unroll
    for (int q = 0; q < 4; ++q) {
        a[2 * q]     += __low2float(cv.h[q]);
        a[2 * q + 1] += __high2float(cv.h[q]);
    }
}

// ---- 8-deep unrolled gather-sum of pre-scaled fp16 rows (G lanes/node)
template <int G>
__device__ inline void gather_sum(const uintx4* __restrict__ H4,
                                  const int* __restrict__ srcSorted,
                                  int s, int e, int lane, float (&acc)[8]) {
    int i = s;
    for (; i + 7 < e; i += 8) {
        int idx[8];
#pragma unroll
        for (int q = 0; q < 8; ++q) idx[q] = srcSorted[i + q];
        uintx4 v[8];
#pragma unroll
        for (int q = 0; q < 8; ++q) v[q] = H4[(size_t)idx[q] * G + lane];
#pragma unroll
        for (int q = 0; q < 8; ++q) add8(acc, v[q]);
    }
    for (; i + 3 < e; i += 4) {
        int idx[4];
#pragma unroll
        for (int q = 0; q < 4; ++q) idx[q] = srcSorted[i + q];
        uintx4 v[4];
#pragma unroll
        for (int q = 0; q < 4; ++q) v[q] = H4[(size_t)idx[q] * G + lane];
#pragma unroll
        for (int q = 0; q < 4; ++q) add8(acc, v[q]);
    }
    for (; i < e; ++i) add8(acc, H4[(size_t)srcSorted[i] * G + lane]);
}

// ---- Fused agg1 + gemm2: per 64-node tile,
// x2 = relu(dn*(sum H1'[s] + H1'[n]) + b1) -> LDS (fp16, swizzled)
// H2' = dinv .* (x2 @ W2) -> global fp16.   H1' is 128-ch, W2 is 128x64.
__global__ __launch_bounds__(256) void agg_gemm_kernel(const __half* __restrict__ H16,
                                                       const int* __restrict__ srcSorted,
                                                       const int* __restrict__ base,
                                                       const float* __restrict__ dinv,
                                                       const float* __restrict__ b1,
                                                       const __half* __restrict__ WT2,
                                                       __half* __restrict__ H2, int N) {
    __shared__ _Float16 sX[64 * 128];
    __shared__ _Float16 sW[64 * 128];
    const int tid = threadIdx.x;
    const int row0 = blockIdx.x * 64;

    // stage W2T (swizzled) early; covered by the sync after agg
    {
        const uintx4* src = (const uintx4*)WT2;
        uintx4* dst = (uintx4*)sW;
        for (int i = tid; i < 64 * 16; i += 256) dst[i] = src[i];
    }

    // ---- agg phase: 4 rounds x 16 nodes, 16 lanes (8 ch each) per node
    const int lane16 = tid & 15;
    const int sub = tid >> 4;
    const uintx4* H4 = (const uintx4*)H16;
    const float4 bb0 = ((const float4*)b1)[lane16 * 2];
    const float4 bb1 = ((const float4*)b1)[lane16 * 2 + 1];

#pragma unroll
    for (int rnd = 0; rnd < 4; ++rnd) {
        const int r = rnd * 16 + sub;
        const int n = row0 + r;
        float o[8];
#pragma unroll
        for (int q = 0; q < 8; ++q) o[q] = 0.f;
        if (n < N) {
            float acc[8];
#pragma unroll
            for (int q = 0; q < 8; ++q) acc[q] = 0.f;
            gather_sum<16>(H4, srcSorted, base[n], base[n + 1], lane16, acc);
            add8(acc, H4[(size_t)n * 16 + lane16]);   // self loop (pre-scaled)
            const float dn = dinv[n];
            o[0] = fmaxf(dn * acc[0] + bb0.x, 0.f);
            o[1] = fmaxf(dn * acc[1] + bb0.y, 0.f);
            o[2] = fmaxf(dn * acc[2] + bb0.z, 0.f);
            o[3] = fmaxf(dn * acc[3] + bb0.w, 0.f);
            o[4] = fmaxf(dn * acc[4] + bb1.x, 0.f);
            o[5] = fmaxf(dn * acc[5] + bb1.y, 0.f);
            o[6] = fmaxf(dn * acc[6] + bb1.z, 0.f);
            o[7] = fmaxf(dn * acc[7] + bb1.w, 0.f);
        }
        half8 h;
#pragma unroll
        for (int q = 0; q < 8; ++q) h[q] = (_Float16)o[q];
        *(half8*)(sX + r * 128 + ((lane16 * 8) ^ ((r & 7) << 3))) = h;
    }
    __syncthreads();

    // ---- MFMA phase (COLS=64): 4 waves, 2M x 2N
    const int w = tid >> 6;
    const int lane = tid & 63;
    const int l15 = lane & 15, l4 = lane >> 4;
    const int wr = (w >> 1) * 32;
    const int wc = (w & 1) * 32;

    half8 a[2][4];
#pragma unroll
    for (int rb = 0; rb < 2; ++rb) {
        int r = wr + rb * 16 + l15;
#pragma unroll
        for (int kb = 0; kb < 4; ++kb)
            a[rb][kb] = *(const half8*)(sX + r * 128 + ((kb * 32 + l4 * 8) ^ ((r & 7) << 3)));
    }

    floatx4 acc[2][2];
#pragma unroll
    for (int rb = 0; rb < 2; ++rb)
#pragma unroll
        for (int cb = 0; cb < 2; ++cb) acc[rb][cb] = (floatx4)(0.f);

#pragma unroll
    for (int cb = 0; cb < 2; ++cb) {
        int c = wc + cb * 16 + l15;
#pragma unroll
        for (int kb = 0; kb < 4; ++kb) {
            half8 b = *(const half8*)(sW + c * 128 + ((kb * 32 + l4 * 8) ^ ((c & 7) << 3)));
#pragma unroll
            for (int rb = 0; rb < 2; ++rb)
                acc[rb][cb] = __builtin_amdgcn_mfma_f32_16x16x32_f16(a[rb][kb], b, acc[rb][cb], 0, 0, 0);
        }
    }

#pragma unroll
    for (int rb = 0; rb < 2; ++rb) {
        float dv[4];
#pragma unroll
        for (int r = 0; r < 4; ++r) {
            int gr = row0 + wr + rb * 16 + l4 * 4 + r;
            dv[r] = (gr < N) ? dinv[gr] : 0.f;
        }
#pragma unroll
        for (int cb = 0; cb < 2; ++cb)
#pragma unroll
            for (int r = 0; r < 4; ++r) {
                int gr = row0 + wr + rb * 16 + l4 * 4 + r;
                if (gr < N) {
                    int gc = wc + cb * 16 + l15;
                    H2[(size_t)gr * 64 + gc] = __float2half_rn(acc[rb][cb][r] * dv[r]);
                }
            }
    }
}

// ---- Final pull aggregation (C=64): out[n] = dn*(sum H'[s] + H'[n]) + b, fp32
__global__ __launch_bounds__(256) void agg_final_kernel(const __half* __restrict__ H16,
                                                        const int* __restrict__ srcSorted,
                                                        const int* __restrict__ base,
                                                        const float* __restrict__ dinv,
                                                        const float* __restrict__ b,
                                                        float* __restrict__ out, int N) {
    constexpr int G = 8;          // 64 ch / 8 per lane
    const int lane = threadIdx.x % G;
    const int sub = threadIdx.x / G;
    const int n = blockIdx.x * 32 + sub;
    if (n >= N) return;

    const uintx4* H4 = (const uintx4*)H16;
    float acc[8];
#pragma unroll
    for (int q = 0; q < 8; ++q) acc[q] = 0.f;
    gather_sum<G>(H4, srcSorted, base[n], base[n + 1], lane, acc);
    add8(acc, H4[(size_t)n * G + lane]);

    const float dn = dinv[n];
    const float4 bb0 = ((const float4*)b)[lane * 2];
    const float4 bb1 = ((const float4*)b)[lane * 2 + 1];
    float o[8];
#pragma unroll
    for (int q = 0; q < 8; ++q) o[q] = dn * acc[q];
    o[0] += bb0.x; o[1] += bb0.y; o[2] += bb0.z; o[3] += bb0.w;
    o[4] += bb1.x; o[5] += bb1.y; o[6] += bb1.z; o[7] += bb1.w;
    float4* op = (float4*)(out + (size_t)n * 64 + lane * 8);
    op[0] = make_float4(o[0], o[1], o[2], o[3]);
    op[1] = make_float4(o[4], o[5], o[6], o[7]);
}

static inline int cdiv(long long a, long long b) { return (int)((a + b - 1) / b); }

extern "C" void kernel_launch(void* const* d_in, const int* in_sizes, int n_in,
                              void* d_out, int out_size, void* d_ws, size_t ws_size,
                              hipStream_t stream) {
    const float* x  = (const float*)d_in[0];
    const float* W1 = (const float*)d_in[1];
    const float* b1 = (const float*)d_in[2];
    const float* W2 = (const float*)d_in[3];
    const float* b2 = (const float*)d_in[4];
    const int*   ei = (const int*)d_in[5];

    const int N = in_sizes[0] / 128;   // 100000
    const int E = in_sizes[5] / 2;     // 1600000
    const int* rows = ei;              // edge_index[0] = source
    const int* cols = ei + E;          // edge_index[1] = target

    const int NSUB = cdiv(N, NBUK);    // 782 nodes per bucket

    char* ws = (char*)d_ws;
    size_t off = 0;
    auto alloc = [&](size_t bytes) {
        size_t p = off;
        off = (off + bytes + 255) & ~(size_t)255;
        return p;
    };
    int*      bcur  = (int*)(ws + alloc((size_t)NBUK * BPAD * 4));
    int*      bbase = (int*)(ws + alloc((size_t)NBUK * 4));
    int*      base  = (int*)(ws + alloc((size_t)(N + 1) * 4));
    float*    dinv  = (float*)(ws + alloc((size_t)N * 4));
    int*      srcS  = (int*)(ws + alloc((size_t)E * 4));
    unsigned* bdata = (unsigned*)(ws + alloc((size_t)NBUK * CAPB * 4));
    __half*   WT1   = (__half*)(ws + alloc((size_t)128 * 128 * 2));
    __half*   WT2   = (__half*)(ws + alloc((size_t)128 * 64 * 2));
    __half*   H16   = (__half*)(ws + alloc((size_t)N * 128 * 2));  // h1'
    __half*   H2    = (__half*)(ws + alloc((size_t)N * 64 * 2));   // h2'
    (void)ws_size;

    float* OUT = (float*)d_out;

    // --- CSR by destination + dinv (shared by both layers) ---
    hipMemsetAsync(bcur, 0, (size_t)NBUK * BPAD * 4, stream);
    bucket_kernel<<<cdiv(E, 4096), 256, 0, stream>>>(rows, cols, E, NSUB, bcur, bdata);
    exscan_bucket_kernel<<<1, NBUK, 0, stream>>>(bcur, bbase, N, base);
    sortfill_kernel<<<NBUK, 256, 0, stream>>>(bdata, bcur, bbase, NSUB, N, base, dinv, srcS);

    // --- weight prep (fp16, transposed, swizzled) ---
    wtrans_kernel<<<cdiv(128 * 128, 256), 256, 0, stream>>>(W1, WT1, 128);
    wtrans_kernel<<<cdiv(128 * 64, 256), 256, 0, stream>>>(W2, WT2, 64);

    // --- layer 1 GEMM ---
    mfma_gemm<128, float><<<cdiv(N, 64), 256, 0, stream>>>(x, WT1, dinv, H16, N);

    // --- fused agg1 + gemm2 ---
    agg_gemm_kernel<<<cdiv(N, 64), 256, 0, stream>>>(H16, srcS, base, dinv, b1, WT2, H2, N);

    // --- final aggregation ---
    agg_final_kernel<<<cdiv(N, 32), 256, 0, stream>>>(H2, srcS, base, dinv, b2, OUT, N);
}